// Round 5
// baseline (1865.280 us; speedup 1.0000x reference)
//
#include <hip/hip_runtime.h>
#include <stdint.h>

#define EPS 1e-5f

typedef __attribute__((ext_vector_type(4))) int i32x4;

// pinned 2-op inner step: v_xor_b32 + accumulating v_bcnt_u32_b32 (fallback path)
__device__ __forceinline__ int xorpop(uint32_t a, uint32_t w, int c)
{
    uint32_t t = a ^ w;
    asm("v_bcnt_u32_b32 %0, %1, %0" : "+v"(c) : "v"(t));
    return c;
}

// ===========================================================================
// ============================  MFMA (new) PATH  ============================
// ===========================================================================

// ---------------------------------------------------------------------------
// conv1 -> a1: fp32 conv 3->384 + BN + sign, output i8 +-1 into padded NHWC
// a1[n][y+1][x+1][co], borders pre-zeroed by memset.
// block=384 (x:32, cog:12), grid=128*32
// ---------------------------------------------------------------------------
__global__ void conv1_a1_kernel(const float* __restrict__ x,
                                const float* __restrict__ w1,
                                const float* __restrict__ g,
                                const float* __restrict__ b,
                                const float* __restrict__ m,
                                const float* __restrict__ v,
                                char* __restrict__ a1)
{
    int bid = blockIdx.x;
    int n = bid >> 5;
    int y = bid & 31;
    int tid = threadIdx.x;
    int xo = tid & 31;
    int cog = tid >> 5;   // 0..11

    float a[27];
#pragma unroll
    for (int ci = 0; ci < 3; ++ci)
#pragma unroll
        for (int dy = 0; dy < 3; ++dy)
#pragma unroll
            for (int dx = 0; dx < 3; ++dx) {
                int yy = y + dy - 1, xx = xo + dx - 1;
                float val = 0.f;
                if (yy >= 0 && yy < 32 && xx >= 0 && xx < 32)
                    val = x[((n * 3 + ci) * 32 + yy) * 32 + xx];
                a[(ci * 3 + dy) * 3 + dx] = val;
            }

    uint32_t w4[8];
#pragma unroll
    for (int i = 0; i < 8; ++i) w4[i] = 0;
    for (int cs = 0; cs < 32; ++cs) {
        int co = cog * 32 + cs;
        const float* wp = w1 + co * 27;
        float acc = 0.f;
#pragma unroll
        for (int i = 0; i < 27; ++i) acc += a[i] * wp[i];
        float t = (acc - m[co]) * (g[co] * rsqrtf(v[co] + EPS)) + b[co];
        uint32_t byte = (t >= 0.f) ? 0x01u : 0xFFu;
        w4[cs >> 2] |= byte << (8 * (cs & 3));
    }
    char* dst = a1 + (((size_t)(n * 34 + y + 1) * 34 + (xo + 1)) * 384 + cog * 32);
    ((uint4*)dst)[0] = make_uint4(w4[0], w4[1], w4[2], w4[3]);
    ((uint4*)dst)[1] = make_uint4(w4[4], w4[5], w4[6], w4[7]);
}

// ---------------------------------------------------------------------------
// weight quantize: w[co][ci][3][3] fp32 -> q[co][tap][ci] i8 +-1
// ---------------------------------------------------------------------------
__global__ void pack_wq_kernel(const float* __restrict__ w,
                               char* __restrict__ q, int Co, int Ci)
{
    int idx = blockIdx.x * 256 + threadIdx.x;
    int total = Co * 9 * Ci;
    if (idx >= total) return;
    int ci  = idx % Ci;
    int t   = idx / Ci;
    int tap = t % 9;
    int co  = t / 9;
    float wv = w[((size_t)co * Ci + ci) * 9 + tap];
    q[idx] = wv >= 0.f ? 1 : -1;
}

// ---------------------------------------------------------------------------
// gemm_bin: implicit-GEMM binary conv via mfma_i32_16x16x64_i8.
// A: padded i8 acts [128][H+2][W+2][Ci] (0 on borders -> padding exact)
// B: i8 weights [Co][9][Ci]
// C: i16 conv output [128*H*W][Co]
// Block: 256 thr = 4 waves (2x2), tile 128M x 128N; wave = 64x64 = 4x4 frags.
// K loop: 9 taps x Ci/64 chunks. A LDS double-buffered [128][80] (pad 16B);
// B loaded global->reg, prefetched one step ahead.
// ---------------------------------------------------------------------------
template<int Ci, int Co, int W, int H>
__global__ __launch_bounds__(256, 2) void gemm_bin_kernel(
    const char* __restrict__ A,
    const char* __restrict__ Bw,
    short* __restrict__ Cc)
{
    constexpr int WP = W + 2;
    constexpr int KC = Ci / 64;
    constexpr int S  = 9 * KC;

    __shared__ __align__(16) char lds[2][128 * 80];

    const int bm = blockIdx.x;
    const int bn = blockIdx.y;
    const int tid = threadIdx.x;
    const int lane = tid & 63;
    const int wave = tid >> 6;
    const int wm = wave >> 1;
    const int wn = wave & 1;
    const int fr = lane & 15;
    const int fg = lane >> 4;

    // staging role: pixel p (0..127), half h (0..1)
    const int p = tid >> 1;
    const int h = tid & 1;
    {
    }
    int gm = bm * 128 + p;
    int n  = gm / (H * W);
    int rr = gm % (H * W);
    int y  = rr / W;
    int x  = rr % W;
    const char* abase = A + ((size_t)(n * (H + 2) + y) * WP + x) * Ci;

    size_t bcol[4];
#pragma unroll
    for (int j = 0; j < 4; ++j) {
        int ncol = bn * 128 + wn * 64 + j * 16 + fr;
        bcol[j] = (size_t)ncol * 9 * Ci;
    }

    int aoff[4];
#pragma unroll
    for (int i = 0; i < 4; ++i)
        aoff[i] = (wm * 64 + i * 16 + fr) * 80 + fg * 16;

    i32x4 acc[4][4] = {};

    // prologue: stage step 0 (tap 0 = dy0,dx0 -> offset 0), load B step 0
    {
        const char* src = abase + h * 32;
        uint4 av0 = *reinterpret_cast<const uint4*>(src);
        uint4 av1 = *reinterpret_cast<const uint4*>(src + 16);
        *reinterpret_cast<uint4*>(&lds[0][p * 80 + h * 32]) = av0;
        *reinterpret_cast<uint4*>(&lds[0][p * 80 + h * 32 + 16]) = av1;
    }
    i32x4 bf[4];
#pragma unroll
    for (int j = 0; j < 4; ++j)
        bf[j] = *reinterpret_cast<const i32x4*>(Bw + bcol[j] + fg * 16);
    __syncthreads();

    for (int s = 0; s < S; ++s) {
        const int cur = s & 1;
        uint4 avn0, avn1;
        i32x4 bfn[4];
        const bool more = (s + 1 < S);
        if (more) {
            int s1 = s + 1;
            int tap = s1 / KC, kc = s1 % KC;
            int dy = tap / 3, dx = tap % 3;
            const char* src = abase + ((dy * WP + dx) * Ci) + kc * 64 + h * 32;
            avn0 = *reinterpret_cast<const uint4*>(src);
            avn1 = *reinterpret_cast<const uint4*>(src + 16);
#pragma unroll
            for (int j = 0; j < 4; ++j)
                bfn[j] = *reinterpret_cast<const i32x4*>(
                    Bw + bcol[j] + (size_t)tap * Ci + kc * 64 + fg * 16);
        }
        i32x4 af[4];
#pragma unroll
        for (int i = 0; i < 4; ++i)
            af[i] = *reinterpret_cast<const i32x4*>(&lds[cur][aoff[i]]);
#pragma unroll
        for (int i = 0; i < 4; ++i)
#pragma unroll
            for (int j = 0; j < 4; ++j)
                acc[i][j] = __builtin_amdgcn_mfma_i32_16x16x64_i8(
                    af[i], bf[j], acc[i][j], 0, 0, 0);
        if (more) {
            *reinterpret_cast<uint4*>(&lds[cur ^ 1][p * 80 + h * 32]) = avn0;
            *reinterpret_cast<uint4*>(&lds[cur ^ 1][p * 80 + h * 32 + 16]) = avn1;
#pragma unroll
            for (int j = 0; j < 4; ++j) bf[j] = bfn[j];
        }
        __syncthreads();
    }

    // epilogue: C row = (lane>>4)*4 + reg, col = lane&15  [m89-verified family]
#pragma unroll
    for (int i = 0; i < 4; ++i) {
        int row = bm * 128 + wm * 64 + i * 16 + fg * 4;
#pragma unroll
        for (int j = 0; j < 4; ++j) {
            int col = bn * 128 + wn * 64 + j * 16 + fr;
#pragma unroll
            for (int r = 0; r < 4; ++r)
                Cc[(size_t)(row + r) * Co + col] = (short)acc[i][j][r];
        }
    }
}

// ---------------------------------------------------------------------------
// pool(optional 2x2) + BN + sign -> i8 +-1 padded NHWC for next layer
// c: i16 [128*H*W][Co]; outp: [128][Ho+2][Wo+2][Co] (borders pre-zeroed)
// ---------------------------------------------------------------------------
__global__ void pool_sign_kernel(const short* __restrict__ c,
                                 const float* __restrict__ g,
                                 const float* __restrict__ b,
                                 const float* __restrict__ m,
                                 const float* __restrict__ v,
                                 char* __restrict__ outp,
                                 int H, int W, int Ho, int Wo, int Co,
                                 int pool, int total)
{
    int idx = blockIdx.x * 256 + threadIdx.x;
    if (idx >= total) return;
    int co = idx % Co;
    int t  = idx / Co;
    int xo = t % Wo; t /= Wo;
    int yo = t % Ho;
    int n  = t / Ho;
    int best;
    if (pool) {
        int m00 = c[((size_t)((n * H + 2 * yo) * W + 2 * xo)) * Co + co];
        int m01 = c[((size_t)((n * H + 2 * yo) * W + 2 * xo + 1)) * Co + co];
        int m10 = c[((size_t)((n * H + 2 * yo + 1) * W + 2 * xo)) * Co + co];
        int m11 = c[((size_t)((n * H + 2 * yo + 1) * W + 2 * xo + 1)) * Co + co];
        best = max(max(m00, m01), max(m10, m11));
    } else {
        best = c[((size_t)((n * H + yo) * W + xo)) * Co + co];
    }
    float tt = ((float)best - m[co]) * (g[co] * rsqrtf(v[co] + EPS)) + b[co];
    outp[((size_t)(n * (Ho + 2) + yo + 1) * (Wo + 2) + xo + 1) * Co + co] =
        tt >= 0.f ? 1 : -1;
}

// ---------------------------------------------------------------------------
// final: pool 2x2 + BN + hardtanh -> fp32 NCHW h6[n][co][yo][xo] (4x4)
// ---------------------------------------------------------------------------
__global__ void pool6_ht_kernel(const short* __restrict__ c,
                                const float* __restrict__ g,
                                const float* __restrict__ b,
                                const float* __restrict__ m,
                                const float* __restrict__ v,
                                float* __restrict__ h6)
{
    int idx = blockIdx.x * 256 + threadIdx.x;
    if (idx >= 128 * 512 * 16) return;
    int xo = idx & 3;
    int yo = (idx >> 2) & 3;
    int t  = idx >> 4;
    int co = t % 512;
    int n  = t / 512;
    int m00 = c[((size_t)((n * 8 + 2 * yo) * 8 + 2 * xo)) * 512 + co];
    int m01 = c[((size_t)((n * 8 + 2 * yo) * 8 + 2 * xo + 1)) * 512 + co];
    int m10 = c[((size_t)((n * 8 + 2 * yo + 1) * 8 + 2 * xo)) * 512 + co];
    int m11 = c[((size_t)((n * 8 + 2 * yo + 1) * 8 + 2 * xo + 1)) * 512 + co];
    int best = max(max(m00, m01), max(m10, m11));
    float tt = ((float)best - m[co]) * (g[co] * rsqrtf(v[co] + EPS)) + b[co];
    tt = fminf(1.f, fmaxf(-1.f, tt));
    h6[((size_t)(n * 512 + co) * 4 + yo) * 4 + xo] = tt;
}

// ===========================================================================
// ==========================  FALLBACK (R3) PATH  ===========================
// ===========================================================================

__global__ void conv1_pack_kernel(const float* __restrict__ x,
                                  const float* __restrict__ w1,
                                  const float* __restrict__ g,
                                  const float* __restrict__ b,
                                  const float* __restrict__ m,
                                  const float* __restrict__ v,
                                  uint32_t* __restrict__ out)
{
    int bid = blockIdx.x;
    int n = bid >> 5;
    int y = bid & 31;
    int tid = threadIdx.x;
    int xo = tid & 31;
    int cog = tid >> 5;

    float a[27];
#pragma unroll
    for (int ci = 0; ci < 3; ++ci)
#pragma unroll
        for (int dy = 0; dy < 3; ++dy)
#pragma unroll
            for (int dx = 0; dx < 3; ++dx) {
                int yy = y + dy - 1, xx = xo + dx - 1;
                float val = 0.f;
                if (yy >= 0 && yy < 32 && xx >= 0 && xx < 32)
                    val = x[((n * 3 + ci) * 32 + yy) * 32 + xx];
                a[(ci * 3 + dy) * 3 + dx] = val;
            }

    uint32_t word = 0;
    for (int cs = 0; cs < 32; ++cs) {
        int co = cog * 32 + cs;
        const float* wp = w1 + co * 27;
        float acc = 0.f;
#pragma unroll
        for (int i = 0; i < 27; ++i) acc += a[i] * wp[i];
        float t = (acc - m[co]) * (g[co] * rsqrtf(v[co] + EPS)) + b[co];
        word |= (uint32_t)(t >= 0.f) << cs;
    }
    out[((n * 32 + y) * 12 + cog) * 32 + xo] = word;
}

__global__ void pack_w2_kernel(const float* __restrict__ w,
                               uint32_t* __restrict__ out,
                               int Co, int Ci)
{
    int CW = Ci >> 5;
    int idx = blockIdx.x * 256 + threadIdx.x;
    int total = 9 * CW * Co;
    if (idx >= total) return;
    int co  = idx % Co;
    int cw  = (idx / Co) % CW;
    int tap = idx / (Co * CW);
    uint32_t word = 0;
    for (int bit = 0; bit < 32; ++bit) {
        float wv = w[(long)co * Ci * 9 + (cw * 32 + bit) * 9 + tap];
        word |= (uint32_t)(wv >= 0.f) << bit;
    }
    out[idx] = word;
}

__global__ void wpop_kernel(const uint32_t* __restrict__ pw,
                            int* __restrict__ wpop, int Co, int CW)
{
    int idx = blockIdx.x * 256 + threadIdx.x;
    if (idx >= 9 * Co) return;
    int co = idx % Co, tap = idx / Co;
    int s = 0;
    for (int cw = 0; cw < CW; ++cw) s += __popc(pw[(tap * CW + cw) * Co + co]);
    wpop[idx] = s;
}

template<int CWIN, int WIN, bool POOL, bool OUTF32, int COB, int XT>
__global__ __launch_bounds__(COB, 2) void bconv2_kernel(
    const uint32_t* __restrict__ act,
    const uint32_t* __restrict__ wgt,
    const int* __restrict__ wpop,
    const float* __restrict__ g, const float* __restrict__ b,
    const float* __restrict__ m, const float* __restrict__ v,
    uint32_t* __restrict__ aout, float* __restrict__ fout,
    int N, int Co)
{
    constexpr int HIN = WIN;
    constexpr int HO = POOL ? WIN / 2 : WIN;
    constexpr int WO = HO;
    constexpr int ROWS = POOL ? 4 : 3;
    constexpr int LW = WIN + 2;
    constexpr int PSUB = POOL ? 2 : 1;
    constexpr int NC = XT * PSUB;
    constexpr int SPAN = NC + 2;

    __shared__ uint32_t lds[ROWS][CWIN][LW];

    const int cbn = Co / COB;
    int bid = blockIdx.x;
    int cb = bid % cbn;
    int yo = (bid / cbn) % HO;
    int n  = bid / (cbn * HO);
    int tid = threadIdx.x;

    {
        int total = ROWS * CWIN * LW;
        int y0 = POOL ? (2 * yo - 1) : (yo - 1);
        for (int idx = tid; idx < total; idx += COB) {
            int xp = idx % LW;
            int cw = (idx / LW) % CWIN;
            int r  = idx / (LW * CWIN);
            int xg = xp - 1;
            int yg = y0 + r;
            uint32_t val = 0;
            if (xg >= 0 && xg < WIN && yg >= 0 && yg < HIN)
                val = act[((n * HIN + yg) * CWIN + cw) * WIN + xg];
            (&lds[0][0][0])[idx] = val;
        }
    }
    __syncthreads();

    int co = cb * COB + tid;
    float scale = g[co] * rsqrtf(v[co] + EPS);
    float mean = m[co], beta = b[co];

    int wp9[9];
#pragma unroll
    for (int t9 = 0; t9 < 9; ++t9) wp9[t9] = wpop[t9 * Co + co];

    int py0 = POOL ? 2 * yo : yo;
    bool rowlo = (py0 == 0);
    bool rowhi = (py0 + PSUB - 1 == HIN - 1);

    for (int xo0 = 0; xo0 < WO; xo0 += XT) {
        int cnt[PSUB][NC];
#pragma unroll
        for (int p = 0; p < PSUB; ++p)
#pragma unroll
            for (int c = 0; c < NC; ++c) cnt[p][c] = 0;

        int xb = xo0 * PSUB;

        for (int cw = 0; cw < CWIN; ++cw) {
            uint32_t wv[9];
#pragma unroll
            for (int t9 = 0; t9 < 9; ++t9)
                wv[t9] = wgt[(t9 * CWIN + cw) * Co + co];
#pragma unroll
            for (int r = 0; r < ROWS; ++r) {
                uint32_t aw[SPAN];
#pragma unroll
                for (int j = 0; j < SPAN; ++j) aw[j] = lds[r][cw][xb + j];
#pragma unroll
                for (int p = 0; p < PSUB; ++p) {
                    int dy = r - p;
                    if (dy < 0 || dy > 2) continue;
#pragma unroll
                    for (int dx = 0; dx < 3; ++dx) {
                        uint32_t w = wv[dy * 3 + dx];
#pragma unroll
                        for (int c = 0; c < NC; ++c)
                            cnt[p][c] = xorpop(aw[c + dx], w, cnt[p][c]);
                    }
                }
            }
        }

#pragma unroll
        for (int q = 0; q < XT; ++q) {
            int xo = xo0 + q;
            float best = -1e30f;
            constexpr int base9 = 9 * 32 * CWIN;
#pragma unroll
            for (int p = 0; p < PSUB; ++p)
#pragma unroll
                for (int cc = 0; cc < PSUB; ++cc) {
                    int c = q * PSUB + cc;
                    int px = xb + c;
                    int dot = base9 - 2 * cnt[p][c];
                    bool plo = rowlo && (p == 0);
                    bool phi = rowhi && (p == PSUB - 1);
                    bool clo = (px == 0);
                    bool chi = (px == WIN - 1);
                    if (plo | phi | clo | chi) {
#pragma unroll
                        for (int dy = 0; dy < 3; ++dy)
#pragma unroll
                            for (int dx = 0; dx < 3; ++dx) {
                                bool inv = (dy == 0 && plo) || (dy == 2 && phi)
                                        || (dx == 0 && clo) || (dx == 2 && chi);
                                if (inv) dot -= 32 * CWIN - 2 * wp9[dy * 3 + dx];
                            }
                    }
                    float fv = (float)dot;
                    best = fmaxf(best, fv);
                }
            float t = (best - mean) * scale + beta;
            if (OUTF32) {
                float ht = fminf(1.f, fmaxf(-1.f, t));
                fout[(((long)n * Co + co) * HO + yo) * WO + xo] = ht;
            } else {
                unsigned long long mask = __ballot(t >= 0.f);
                int lane = tid & 63;
                if ((lane & 31) == 0) {
                    uint32_t wrd = (uint32_t)(mask >> (lane & 32));
                    int cog = co >> 5;
                    aout[((n * HO + yo) * (Co >> 5) + cog) * WO + xo] = wrd;
                }
            }
        }
    }
}

// ---------------------------------------------------------------------------
// classifier: logits = h @ w_lin.T (128 x 8192 x 10) then log_softmax
// ---------------------------------------------------------------------------
__global__ void classifier_kernel(const float* __restrict__ h,
                                  const float* __restrict__ wl,
                                  float* __restrict__ out)
{
    int n = blockIdx.x;
    int tid = threadIdx.x;
    float acc[10];
#pragma unroll
    for (int j = 0; j < 10; ++j) acc[j] = 0.f;
    for (int k = tid; k < 8192; k += 256) {
        float hv = h[n * 8192 + k];
#pragma unroll
        for (int j = 0; j < 10; ++j) acc[j] += hv * wl[j * 8192 + k];
    }
    __shared__ float sred[256];
    __shared__ float logit[10];
    for (int j = 0; j < 10; ++j) {
        sred[tid] = acc[j];
        __syncthreads();
        for (int s = 128; s > 0; s >>= 1) {
            if (tid < s) sred[tid] += sred[tid + s];
            __syncthreads();
        }
        if (tid == 0) logit[j] = sred[0];
        __syncthreads();
    }
    if (tid == 0) {
        float mx = logit[0];
#pragma unroll
        for (int j = 1; j < 10; ++j) mx = fmaxf(mx, logit[j]);
        float s = 0.f;
#pragma unroll
        for (int j = 0; j < 10; ++j) s += expf(logit[j] - mx);
        float lse = logf(s) + mx;
#pragma unroll
        for (int j = 0; j < 10; ++j) out[n * 10 + j] = logit[j] - lse;
    }
}

// ===========================================================================
extern "C" void kernel_launch(void* const* d_in, const int* in_sizes, int n_in,
                              void* d_out, int out_size, void* d_ws, size_t ws_size,
                              hipStream_t stream)
{
    const float* x    = (const float*)d_in[0];
    const float* w1   = (const float*)d_in[1];
    const float* w2   = (const float*)d_in[2];
    const float* w3   = (const float*)d_in[3];
    const float* w4   = (const float*)d_in[4];
    const float* w5   = (const float*)d_in[5];
    const float* w6   = (const float*)d_in[6];
    const float* bn_g[6], *bn_b[6], *bn_m[6], *bn_v[6];
    for (int i = 0; i < 6; ++i) {
        bn_g[i] = (const float*)d_in[7 + i * 4 + 0];
        bn_b[i] = (const float*)d_in[7 + i * 4 + 1];
        bn_m[i] = (const float*)d_in[7 + i * 4 + 2];
        bn_v[i] = (const float*)d_in[7 + i * 4 + 3];
    }
    const float* wlin = (const float*)d_in[31];
    float* out = (float*)d_out;

    // ---- MFMA path workspace plan (3 rotating slots + weights) ----
    const size_t A1 = (size_t)128 * 34 * 34 * 384;     // 56.8 MB
    const size_t A2 = (size_t)128 * 18 * 18 * 384;
    const size_t A3 = (size_t)128 * 18 * 18 * 768;
    const size_t A4 = (size_t)128 * 10 * 10 * 768;
    const size_t A5 = (size_t)128 * 10 * 10 * 1536;
    const size_t C2 = (size_t)131072 * 384 * 2;        // 100.7 MB
    const size_t C3 = (size_t)32768 * 768 * 2;
    const size_t C4 = C3;
    const size_t C5 = (size_t)8192 * 1536 * 2;
    const size_t C6 = (size_t)8192 * 512 * 2;
    const size_t H6 = (size_t)128 * 8192 * 4;
    const size_t S0 = A1;                               // >= C3, A4, C6
    const size_t S1 = C2;                               // >= A3, C5, H6
    const size_t S2 = C4;                               // >= A2, A5
    const size_t QW = (size_t)(384 * 9 * 384 + 768 * 9 * 384 + 768 * 9 * 768 +
                               1536 * 9 * 768 + 512 * 9 * 1536);
    const size_t NEED = S0 + S1 + S2 + QW + 4096;

    if (ws_size >= NEED) {
        // =======================  MFMA PATH  =======================
        char* ws = (char*)d_ws;
        auto alloc = [&](size_t bytes) {
            char* p = ws;
            ws += (bytes + 255) & ~(size_t)255;
            return p;
        };
        char* s0 = (char*)alloc(S0);
        char* s1 = (char*)alloc(S1);
        char* s2 = (char*)alloc(S2);
        char* qw2 = (char*)alloc((size_t)384 * 9 * 384);
        char* qw3 = (char*)alloc((size_t)768 * 9 * 384);
        char* qw4 = (char*)alloc((size_t)768 * 9 * 768);
        char* qw5 = (char*)alloc((size_t)1536 * 9 * 768);
        char* qw6 = (char*)alloc((size_t)512 * 9 * 1536);

        char*  a1 = s0;
        short* c2 = (short*)s1;
        char*  a2 = s2;
        short* c3 = (short*)s0;
        char*  a3 = s1;
        short* c4 = (short*)s2;
        char*  a4 = s0;
        short* c5 = (short*)s1;
        char*  a5 = s2;
        short* c6 = (short*)s0;
        float* h6 = (float*)s1;

        // weight quantize
        {
            int t;
            t = 384 * 9 * 384;
            pack_wq_kernel<<<(t + 255) / 256, 256, 0, stream>>>(w2, qw2, 384, 384);
            t = 768 * 9 * 384;
            pack_wq_kernel<<<(t + 255) / 256, 256, 0, stream>>>(w3, qw3, 768, 384);
            t = 768 * 9 * 768;
            pack_wq_kernel<<<(t + 255) / 256, 256, 0, stream>>>(w4, qw4, 768, 768);
            t = 1536 * 9 * 768;
            pack_wq_kernel<<<(t + 255) / 256, 256, 0, stream>>>(w5, qw5, 1536, 768);
            t = 512 * 9 * 1536;
            pack_wq_kernel<<<(t + 255) / 256, 256, 0, stream>>>(w6, qw6, 512, 1536);
        }

        // block 1 -> a1 (padded i8)
        hipMemsetAsync(a1, 0, A1, stream);
        conv1_a1_kernel<<<128 * 32, 384, 0, stream>>>(
            x, w1, bn_g[0], bn_b[0], bn_m[0], bn_v[0], a1);

        // L2: a1 x qw2 -> c2
        gemm_bin_kernel<384, 384, 32, 32><<<dim3(1024, 3), 256, 0, stream>>>(a1, qw2, c2);
        // pool2 -> a2
        hipMemsetAsync(a2, 0, A2, stream);
        {
            int total = 128 * 16 * 16 * 384;
            pool_sign_kernel<<<(total + 255) / 256, 256, 0, stream>>>(
                c2, bn_g[1], bn_b[1], bn_m[1], bn_v[1], a2, 32, 32, 16, 16, 384, 1, total);
        }
        // L3: a2 x qw3 -> c3
        gemm_bin_kernel<384, 768, 16, 16><<<dim3(256, 6), 256, 0, stream>>>(a2, qw3, c3);
        // sign3 -> a3
        hipMemsetAsync(a3, 0, A3, stream);
        {
            int total = 128 * 16 * 16 * 768;
            pool_sign_kernel<<<(total + 255) / 256, 256, 0, stream>>>(
                c3, bn_g[2], bn_b[2], bn_m[2], bn_v[2], a3, 16, 16, 16, 16, 768, 0, total);
        }
        // L4: a3 x qw4 -> c4
        gemm_bin_kernel<768, 768, 16, 16><<<dim3(256, 6), 256, 0, stream>>>(a3, qw4, c4);
        // pool4 -> a4
        hipMemsetAsync(a4, 0, A4, stream);
        {
            int total = 128 * 8 * 8 * 768;
            pool_sign_kernel<<<(total + 255) / 256, 256, 0, stream>>>(
                c4, bn_g[3], bn_b[3], bn_m[3], bn_v[3], a4, 16, 16, 8, 8, 768, 1, total);
        }
        // L5: a4 x qw5 -> c5
        gemm_bin_kernel<768, 1536, 8, 8><<<dim3(64, 12), 256, 0, stream>>>(a4, qw5, c5);
        // sign5 -> a5
        hipMemsetAsync(a5, 0, A5, stream);
        {
            int total = 128 * 8 * 8 * 1536;
            pool_sign_kernel<<<(total + 255) / 256, 256, 0, stream>>>(
                c5, bn_g[4], bn_b[4], bn_m[4], bn_v[4], a5, 8, 8, 8, 8, 1536, 0, total);
        }
        // L6: a5 x qw6 -> c6
        gemm_bin_kernel<1536, 512, 8, 8><<<dim3(64, 4), 256, 0, stream>>>(a5, qw6, c6);
        // pool6 + hardtanh -> h6 (fp32 NCHW)
        {
            int total = 128 * 512 * 16;
            pool6_ht_kernel<<<(total + 255) / 256, 256, 0, stream>>>(
                c6, bn_g[5], bn_b[5], bn_m[5], bn_v[5], h6);
        }
        classifier_kernel<<<128, 256, 0, stream>>>(h6, wlin, out);
        return;
    }

    // =======================  FALLBACK (R3) PATH  =======================
    char* ws = (char*)d_ws;
    auto alloc = [&](size_t bytes) {
        char* p = ws;
        ws += (bytes + 255) & ~(size_t)255;
        return p;
    };
    uint32_t* pw2 = (uint32_t*)alloc((size_t)9 * 12 * 384 * 4);
    uint32_t* pw3 = (uint32_t*)alloc((size_t)9 * 12 * 768 * 4);
    uint32_t* pw4 = (uint32_t*)alloc((size_t)9 * 24 * 768 * 4);
    uint32_t* pw5 = (uint32_t*)alloc((size_t)9 * 24 * 1536 * 4);
    uint32_t* pw6 = (uint32_t*)alloc((size_t)9 * 48 * 512 * 4);
    int* wp2 = (int*)alloc((size_t)9 * 384 * 4);
    int* wp3 = (int*)alloc((size_t)9 * 768 * 4);
    int* wp4 = (int*)alloc((size_t)9 * 768 * 4);
    int* wp5 = (int*)alloc((size_t)9 * 1536 * 4);
    int* wp6 = (int*)alloc((size_t)9 * 512 * 4);
    uint32_t* s1b = (uint32_t*)alloc((size_t)128 * 32 * 12 * 32 * 4);
    uint32_t* s2b = (uint32_t*)alloc((size_t)128 * 16 * 12 * 16 * 4);
    uint32_t* s3b = (uint32_t*)alloc((size_t)128 * 16 * 24 * 16 * 4);
    uint32_t* s4b = (uint32_t*)alloc((size_t)128 * 8 * 24 * 8 * 4);
    uint32_t* s5b = (uint32_t*)alloc((size_t)128 * 8 * 48 * 8 * 4);
    float*    h6b = (float*)alloc((size_t)128 * 512 * 16 * 4);

    {
        int t2 = 9 * 12 * 384, t3 = 9 * 12 * 768, t4 = 9 * 24 * 768,
            t5 = 9 * 24 * 1536, t6 = 9 * 48 * 512;
        pack_w2_kernel<<<(t2 + 255) / 256, 256, 0, stream>>>(w2, pw2, 384, 384);
        pack_w2_kernel<<<(t3 + 255) / 256, 256, 0, stream>>>(w3, pw3, 768, 384);
        pack_w2_kernel<<<(t4 + 255) / 256, 256, 0, stream>>>(w4, pw4, 768, 768);
        pack_w2_kernel<<<(t5 + 255) / 256, 256, 0, stream>>>(w5, pw5, 1536, 768);
        pack_w2_kernel<<<(t6 + 255) / 256, 256, 0, stream>>>(w6, pw6, 512, 1536);
        wpop_kernel<<<(9 * 384 + 255) / 256, 256, 0, stream>>>(pw2, wp2, 384, 12);
        wpop_kernel<<<(9 * 768 + 255) / 256, 256, 0, stream>>>(pw3, wp3, 768, 12);
        wpop_kernel<<<(9 * 768 + 255) / 256, 256, 0, stream>>>(pw4, wp4, 768, 24);
        wpop_kernel<<<(9 * 1536 + 255) / 256, 256, 0, stream>>>(pw5, wp5, 1536, 24);
        wpop_kernel<<<(9 * 512 + 255) / 256, 256, 0, stream>>>(pw6, wp6, 512, 48);
    }

    conv1_pack_kernel<<<128 * 32, 384, 0, stream>>>(
        x, w1, bn_g[0], bn_b[0], bn_m[0], bn_v[0], s1b);

    bconv2_kernel<12, 32, true, false, 384, 16><<<128 * 16, 384, 0, stream>>>(
        s1b, pw2, wp2, bn_g[1], bn_b[1], bn_m[1], bn_v[1], s2b, nullptr, 128, 384);
    bconv2_kernel<12, 16, false, false, 768, 16><<<128 * 16, 768, 0, stream>>>(
        s2b, pw3, wp3, bn_g[2], bn_b[2], bn_m[2], bn_v[2], s3b, nullptr, 128, 768);
    bconv2_kernel<24, 16, true, false, 768, 8><<<128 * 8, 768, 0, stream>>>(
        s3b, pw4, wp4, bn_g[3], bn_b[3], bn_m[3], bn_v[3], s4b, nullptr, 128, 768);
    bconv2_kernel<24, 8, false, false, 768, 8><<<128 * 8 * 2, 768, 0, stream>>>(
        s4b, pw5, wp5, bn_g[4], bn_b[4], bn_m[4], bn_v[4], s5b, nullptr, 128, 1536);
    bconv2_kernel<48, 8, true, true, 512, 4><<<128 * 4, 512, 0, stream>>>(
        s5b, pw6, wp6, bn_g[5], bn_b[5], bn_m[5], bn_v[5], nullptr, h6b, 128, 512);

    classifier_kernel<<<128, 256, 0, stream>>>(h6b, wlin, out);
}

// Round 6
// 1717.632 us; speedup vs baseline: 1.0860x; 1.0860x over previous
//
#include <hip/hip_runtime.h>
#include <stdint.h>

#define EPS 1e-5f

typedef __attribute__((ext_vector_type(4))) int i32x4;

// ---------------------------------------------------------------------------
// conv1 -> a1: fp32 conv 3->384 + BN + sign, output i8 +-1 into padded NHWC
// a1[n][y+1][x+1][co], borders pre-zeroed by memset.
// ---------------------------------------------------------------------------
__global__ void conv1_a1_kernel(const float* __restrict__ x,
                                const float* __restrict__ w1,
                                const float* __restrict__ g,
                                const float* __restrict__ b,
                                const float* __restrict__ m,
                                const float* __restrict__ v,
                                char* __restrict__ a1)
{
    int bid = blockIdx.x;
    int n = bid >> 5;
    int y = bid & 31;
    int tid = threadIdx.x;
    int xo = tid & 31;
    int cog = tid >> 5;   // 0..11

    float a[27];
#pragma unroll
    for (int ci = 0; ci < 3; ++ci)
#pragma unroll
        for (int dy = 0; dy < 3; ++dy)
#pragma unroll
            for (int dx = 0; dx < 3; ++dx) {
                int yy = y + dy - 1, xx = xo + dx - 1;
                float val = 0.f;
                if (yy >= 0 && yy < 32 && xx >= 0 && xx < 32)
                    val = x[((n * 3 + ci) * 32 + yy) * 32 + xx];
                a[(ci * 3 + dy) * 3 + dx] = val;
            }

    uint32_t w4[8];
#pragma unroll
    for (int i = 0; i < 8; ++i) w4[i] = 0;
    for (int cs = 0; cs < 32; ++cs) {
        int co = cog * 32 + cs;
        const float* wp = w1 + co * 27;
        float acc = 0.f;
#pragma unroll
        for (int i = 0; i < 27; ++i) acc += a[i] * wp[i];
        float t = (acc - m[co]) * (g[co] * rsqrtf(v[co] + EPS)) + b[co];
        uint32_t byte = (t >= 0.f) ? 0x01u : 0xFFu;
        w4[cs >> 2] |= byte << (8 * (cs & 3));
    }
    char* dst = a1 + (((size_t)(n * 34 + y + 1) * 34 + (xo + 1)) * 384 + cog * 32);
    ((uint4*)dst)[0] = make_uint4(w4[0], w4[1], w4[2], w4[3]);
    ((uint4*)dst)[1] = make_uint4(w4[4], w4[5], w4[6], w4[7]);
}

// ---------------------------------------------------------------------------
// B repack into fragment order: Bp[s][col][fg*16+t], s = tap*KC+kc,
// element = sign(w[col][ci=kc*64+fg*16+t][tap]).  Per-step wave loads become
// fully-coalesced 1KB dwordx4 bursts (R4's 3456B-stride gather removed).
// ---------------------------------------------------------------------------
__global__ void pack_bp_kernel(const float* __restrict__ w,
                               char* __restrict__ bp, int Co, int Ci)
{
    int KC = Ci >> 6;
    int idx = blockIdx.x * 256 + threadIdx.x;
    int total = Co * 9 * Ci;
    if (idx >= total) return;
    int t  = idx & 15;
    int fg = (idx >> 4) & 3;
    int co = (idx >> 6) % Co;
    int s  = idx / (Co * 64);
    int tap = s / KC, kc = s % KC;
    int ci = kc * 64 + fg * 16 + t;
    bp[idx] = (w[((size_t)co * Ci + ci) * 9 + tap] >= 0.f) ? 1 : -1;
}

// ---------------------------------------------------------------------------
// gemm_patch: patch-resident implicit-GEMM binary conv, mfma_i32_16x16x64_i8.
// Block stages a (TR+2)x(TC+2)xCi zero-padded patch to LDS ONCE (1 barrier),
// then streams 9*KC K-steps of {coalesced B prefetch + ds_read_b128 + MFMA}
// with no further syncs (taps = LDS address offsets -> 9x less A traffic).
// Row stride RS=Ci+16: (RS/4)%32==4 -> even bank-quad spread, conflict-free.
// 4 waves (WMxWN); wave tile = (M/WM) x (128/WN); MI x NJ 16x16 frags.
// ---------------------------------------------------------------------------
template<int Ci, int Co, int H, int W, int TR, int TC, int WM, int WN, int MINW>
__global__ __launch_bounds__(256, MINW) void gemm_patch_kernel(
    const char* __restrict__ A,
    const char* __restrict__ Bp,
    short* __restrict__ Cc)
{
    constexpr int M  = TR * TC;
    constexpr int KC = Ci / 64;
    constexpr int RS = Ci + 16;
    constexpr int PH = TR + 2, PW = TC + 2;
    constexpr int GR = Ci / 16;
    constexpr int waveM = M / WM;
    constexpr int waveN = 128 / WN;
    constexpr int MI = waveM / 16;
    constexpr int NJ = waveN / 16;
    constexpr int TX = W / TC, TY = H / TR;

    __shared__ __align__(16) char lds[PH * PW * RS];

    const int bm = blockIdx.x, bn = blockIdx.y;
    const int tx = bm % TX;
    const int ty = (bm / TX) % TY;
    const int n  = bm / (TX * TY);
    const int tid = threadIdx.x;
    const int lane = tid & 63;
    const int wave = tid >> 6;
    const int wm = wave / WN, wn = wave % WN;
    const int fr = lane & 15, fg = lane >> 4;

    // one-time patch staging (A is pre-padded -> no bounds checks)
    {
        const char* srcbase =
            A + ((size_t)(n * (H + 2) + ty * TR) * (W + 2) + tx * TC) * Ci;
        constexpr int TOT = PH * PW * GR;
        for (int u = tid; u < TOT; u += 256) {
            int g = u % GR, pix = u / GR;
            int pp = pix / PW, qq = pix % PW;
            *reinterpret_cast<uint4*>(&lds[pix * RS + g * 16]) =
                *reinterpret_cast<const uint4*>(
                    srcbase + ((size_t)pp * (W + 2) + qq) * Ci + g * 16);
        }
    }

    int ab[MI];
#pragma unroll
    for (int i = 0; i < MI; ++i) {
        int p = wm * waveM + i * 16 + fr;
        ab[i] = ((p / TC) * PW + (p % TC)) * RS + fg * 16;
    }
    size_t boff[NJ];
#pragma unroll
    for (int j = 0; j < NJ; ++j) {
        int col = bn * 128 + wn * waveN + j * 16 + fr;
        boff[j] = (size_t)col * 64 + (size_t)fg * 16;
    }
    const size_t bstep = (size_t)Co * 64;

    i32x4 bf[NJ];
#pragma unroll
    for (int j = 0; j < NJ; ++j)
        bf[j] = *reinterpret_cast<const i32x4*>(Bp + boff[j]);

    i32x4 acc[MI][NJ] = {};
    __syncthreads();

    for (int tap = 0; tap < 9; ++tap) {
        const int toff = ((tap / 3) * PW + (tap % 3)) * RS;
#pragma unroll
        for (int kc = 0; kc < KC; ++kc) {
            // prefetch next step's B (Bp padded by one step -> no branch)
            const size_t snext = (size_t)(tap * KC + kc + 1);
            i32x4 bfn[NJ];
#pragma unroll
            for (int j = 0; j < NJ; ++j)
                bfn[j] = *reinterpret_cast<const i32x4*>(
                    Bp + snext * bstep + boff[j]);
            i32x4 af[MI];
#pragma unroll
            for (int i = 0; i < MI; ++i)
                af[i] = *reinterpret_cast<const i32x4*>(
                    &lds[ab[i] + toff + kc * 64]);
#pragma unroll
            for (int i = 0; i < MI; ++i)
#pragma unroll
                for (int j = 0; j < NJ; ++j)
                    acc[i][j] = __builtin_amdgcn_mfma_i32_16x16x64_i8(
                        af[i], bf[j], acc[i][j], 0, 0, 0);
#pragma unroll
            for (int j = 0; j < NJ; ++j) bf[j] = bfn[j];
        }
    }

    // epilogue: frag row = i*16 + fg*4 + r, col = j*16 + fr (R4-verified map)
#pragma unroll
    for (int i = 0; i < MI; ++i) {
#pragma unroll
        for (int r = 0; r < 4; ++r) {
            int p = wm * waveM + i * 16 + fg * 4 + r;
            int y = ty * TR + p / TC;
            int x = tx * TC + p % TC;
            size_t crow = ((size_t)(n * H + y) * W + x) * Co;
#pragma unroll
            for (int j = 0; j < NJ; ++j) {
                int col = bn * 128 + wn * waveN + j * 16 + fr;
                Cc[crow + col] = (short)acc[i][j][r];
            }
        }
    }
}

// ---------------------------------------------------------------------------
// pool(optional 2x2) + BN + sign -> i8 +-1 padded NHWC for next layer
// ---------------------------------------------------------------------------
__global__ void pool_sign_kernel(const short* __restrict__ c,
                                 const float* __restrict__ g,
                                 const float* __restrict__ b,
                                 const float* __restrict__ m,
                                 const float* __restrict__ v,
                                 char* __restrict__ outp,
                                 int H, int W, int Ho, int Wo, int Co,
                                 int pool, int total)
{
    int idx = blockIdx.x * 256 + threadIdx.x;
    if (idx >= total) return;
    int co = idx % Co;
    int t  = idx / Co;
    int xo = t % Wo; t /= Wo;
    int yo = t % Ho;
    int n  = t / Ho;
    int best;
    if (pool) {
        int m00 = c[((size_t)((n * H + 2 * yo) * W + 2 * xo)) * Co + co];
        int m01 = c[((size_t)((n * H + 2 * yo) * W + 2 * xo + 1)) * Co + co];
        int m10 = c[((size_t)((n * H + 2 * yo + 1) * W + 2 * xo)) * Co + co];
        int m11 = c[((size_t)((n * H + 2 * yo + 1) * W + 2 * xo + 1)) * Co + co];
        best = max(max(m00, m01), max(m10, m11));
    } else {
        best = c[((size_t)((n * H + yo) * W + xo)) * Co + co];
    }
    float tt = ((float)best - m[co]) * (g[co] * rsqrtf(v[co] + EPS)) + b[co];
    outp[((size_t)(n * (Ho + 2) + yo + 1) * (Wo + 2) + xo + 1) * Co + co] =
        tt >= 0.f ? 1 : -1;
}

// ---------------------------------------------------------------------------
// final: pool 2x2 + BN + hardtanh -> fp32 NCHW h6[n][co][yo][xo] (4x4)
// ---------------------------------------------------------------------------
__global__ void pool6_ht_kernel(const short* __restrict__ c,
                                const float* __restrict__ g,
                                const float* __restrict__ b,
                                const float* __restrict__ m,
                                const float* __restrict__ v,
                                float* __restrict__ h6)
{
    int idx = blockIdx.x * 256 + threadIdx.x;
    if (idx >= 128 * 512 * 16) return;
    int xo = idx & 3;
    int yo = (idx >> 2) & 3;
    int t  = idx >> 4;
    int co = t % 512;
    int n  = t / 512;
    int m00 = c[((size_t)((n * 8 + 2 * yo) * 8 + 2 * xo)) * 512 + co];
    int m01 = c[((size_t)((n * 8 + 2 * yo) * 8 + 2 * xo + 1)) * 512 + co];
    int m10 = c[((size_t)((n * 8 + 2 * yo + 1) * 8 + 2 * xo)) * 512 + co];
    int m11 = c[((size_t)((n * 8 + 2 * yo + 1) * 8 + 2 * xo + 1)) * 512 + co];
    int best = max(max(m00, m01), max(m10, m11));
    float tt = ((float)best - m[co]) * (g[co] * rsqrtf(v[co] + EPS)) + b[co];
    tt = fminf(1.f, fmaxf(-1.f, tt));
    h6[((size_t)(n * 512 + co) * 4 + yo) * 4 + xo] = tt;
}

// ---------------------------------------------------------------------------
// classifier: logits = h @ w_lin.T (128 x 8192 x 10) then log_softmax
// ---------------------------------------------------------------------------
__global__ void classifier_kernel(const float* __restrict__ h,
                                  const float* __restrict__ wl,
                                  float* __restrict__ out)
{
    int n = blockIdx.x;
    int tid = threadIdx.x;
    float acc[10];
#pragma unroll
    for (int j = 0; j < 10; ++j) acc[j] = 0.f;
    for (int k = tid; k < 8192; k += 256) {
        float hv = h[n * 8192 + k];
#pragma unroll
        for (int j = 0; j < 10; ++j) acc[j] += hv * wl[j * 8192 + k];
    }
    __shared__ float sred[256];
    __shared__ float logit[10];
    for (int j = 0; j < 10; ++j) {
        sred[tid] = acc[j];
        __syncthreads();
        for (int s = 128; s > 0; s >>= 1) {
            if (tid < s) sred[tid] += sred[tid + s];
            __syncthreads();
        }
        if (tid == 0) logit[j] = sred[0];
        __syncthreads();
    }
    if (tid == 0) {
        float mx = logit[0];
#pragma unroll
        for (int j = 1; j < 10; ++j) mx = fmaxf(mx, logit[j]);
        float s = 0.f;
#pragma unroll
        for (int j = 0; j < 10; ++j) s += expf(logit[j] - mx);
        float lse = logf(s) + mx;
#pragma unroll
        for (int j = 0; j < 10; ++j) out[n * 10 + j] = logit[j] - lse;
    }
}

// ===========================================================================
extern "C" void kernel_launch(void* const* d_in, const int* in_sizes, int n_in,
                              void* d_out, int out_size, void* d_ws, size_t ws_size,
                              hipStream_t stream)
{
    const float* x    = (const float*)d_in[0];
    const float* w1   = (const float*)d_in[1];
    const float* w2   = (const float*)d_in[2];
    const float* w3   = (const float*)d_in[3];
    const float* w4   = (const float*)d_in[4];
    const float* w5   = (const float*)d_in[5];
    const float* w6   = (const float*)d_in[6];
    const float* bn_g[6], *bn_b[6], *bn_m[6], *bn_v[6];
    for (int i = 0; i < 6; ++i) {
        bn_g[i] = (const float*)d_in[7 + i * 4 + 0];
        bn_b[i] = (const float*)d_in[7 + i * 4 + 1];
        bn_m[i] = (const float*)d_in[7 + i * 4 + 2];
        bn_v[i] = (const float*)d_in[7 + i * 4 + 3];
    }
    const float* wlin = (const float*)d_in[31];
    float* out = (float*)d_out;

    // rotating activation/conv-out slots (same liveness plan as R4, verified)
    const size_t A1 = (size_t)128 * 34 * 34 * 384;     // 56.8 MB
    const size_t A2 = (size_t)128 * 18 * 18 * 384;
    const size_t A3 = (size_t)128 * 18 * 18 * 768;
    const size_t A4 = (size_t)128 * 10 * 10 * 768;
    const size_t A5 = (size_t)128 * 10 * 10 * 1536;
    const size_t C2 = (size_t)131072 * 384 * 2;        // 100.7 MB
    const size_t C4 = (size_t)32768 * 768 * 2;         // 50.3 MB
    const size_t S0 = A1;                              // holds a1,c3,a4,c6
    const size_t S1 = C2;                              // holds c2,a3,c5,h6
    const size_t S2 = C4;                              // holds a2,c4,a5

    char* ws = (char*)d_ws;
    auto alloc = [&](size_t bytes) {
        char* p = ws;
        ws += (bytes + 255) & ~(size_t)255;
        return p;
    };
    char* s0 = (char*)alloc(S0);
    char* s1 = (char*)alloc(S1);
    char* s2 = (char*)alloc(S2);
    // B packs, padded by one K-step (always-prefetch reads one past the end)
    char* bp2 = (char*)alloc((size_t)(9 * 6 + 1) * 384 * 64);
    char* bp3 = (char*)alloc((size_t)(9 * 6 + 1) * 768 * 64);
    char* bp4 = (char*)alloc((size_t)(9 * 12 + 1) * 768 * 64);
    char* bp5 = (char*)alloc((size_t)(9 * 12 + 1) * 1536 * 64);
    char* bp6 = (char*)alloc((size_t)(9 * 24 + 1) * 512 * 64);

    char*  a1 = s0;
    short* c2 = (short*)s1;
    char*  a2 = s2;
    short* c3 = (short*)s0;
    char*  a3 = s1;
    short* c4 = (short*)s2;
    char*  a4 = s0;
    short* c5 = (short*)s1;
    char*  a5 = s2;
    short* c6 = (short*)s0;
    float* h6 = (float*)s1;

    // B repacks
    {
        int t;
        t = 384 * 9 * 384;
        pack_bp_kernel<<<(t + 255) / 256, 256, 0, stream>>>(w2, bp2, 384, 384);
        t = 768 * 9 * 384;
        pack_bp_kernel<<<(t + 255) / 256, 256, 0, stream>>>(w3, bp3, 768, 384);
        t = 768 * 9 * 768;
        pack_bp_kernel<<<(t + 255) / 256, 256, 0, stream>>>(w4, bp4, 768, 768);
        t = 1536 * 9 * 768;
        pack_bp_kernel<<<(t + 255) / 256, 256, 0, stream>>>(w5, bp5, 1536, 768);
        t = 512 * 9 * 1536;
        pack_bp_kernel<<<(t + 255) / 256, 256, 0, stream>>>(w6, bp6, 512, 1536);
    }

    // block 1 -> a1 (padded i8)
    hipMemsetAsync(a1, 0, A1, stream);
    conv1_a1_kernel<<<128 * 32, 384, 0, stream>>>(
        x, w1, bn_g[0], bn_b[0], bn_m[0], bn_v[0], a1);

    // L2: 384->384 @32x32. tile 8x16, waves 2x2, LDS 72.0KB, 2/CU
    gemm_patch_kernel<384, 384, 32, 32, 8, 16, 2, 2, 2>
        <<<dim3(1024, 3), 256, 0, stream>>>(a1, bp2, c2);
    hipMemsetAsync(a2, 0, A2, stream);
    {
        int total = 128 * 16 * 16 * 384;
        pool_sign_kernel<<<(total + 255) / 256, 256, 0, stream>>>(
            c2, bn_g[1], bn_b[1], bn_m[1], bn_v[1], a2, 32, 32, 16, 16, 384, 1, total);
    }
    // L3: 384->768 @16x16. tile 8x16, LDS 72.0KB, 2/CU
    gemm_patch_kernel<384, 768, 16, 16, 8, 16, 2, 2, 2>
        <<<dim3(256, 6), 256, 0, stream>>>(a2, bp3, c3);
    hipMemsetAsync(a3, 0, A3, stream);
    {
        int total = 128 * 16 * 16 * 768;
        pool_sign_kernel<<<(total + 255) / 256, 256, 0, stream>>>(
            c3, bn_g[2], bn_b[2], bn_m[2], bn_v[2], a3, 16, 16, 16, 16, 768, 0, total);
    }
    // L4: 768->768 @16x16. tile 2x16 (M=32), waves 1x4, LDS 56.4KB, 2/CU
    gemm_patch_kernel<768, 768, 16, 16, 2, 16, 1, 4, 2>
        <<<dim3(1024, 6), 256, 0, stream>>>(a3, bp4, c4);
    hipMemsetAsync(a4, 0, A4, stream);
    {
        int total = 128 * 8 * 8 * 768;
        pool_sign_kernel<<<(total + 255) / 256, 256, 0, stream>>>(
            c4, bn_g[3], bn_b[3], bn_m[3], bn_v[3], a4, 16, 16, 8, 8, 768, 1, total);
    }
    // L5: 768->1536 @8x8. tile 8x8 (M=64), waves 2x2, LDS 78.4KB, 2/CU
    gemm_patch_kernel<768, 1536, 8, 8, 8, 8, 2, 2, 2>
        <<<dim3(128, 12), 256, 0, stream>>>(a4, bp5, c5);
    hipMemsetAsync(a5, 0, A5, stream);
    {
        int total = 128 * 8 * 8 * 1536;
        pool_sign_kernel<<<(total + 255) / 256, 256, 0, stream>>>(
            c5, bn_g[4], bn_b[4], bn_m[4], bn_v[4], a5, 8, 8, 8, 8, 1536, 0, total);
    }
    // L6: 1536->512 @8x8. tile 4x8 (M=32), waves 1x4, LDS 93.1KB, 1/CU
    gemm_patch_kernel<1536, 512, 8, 8, 4, 8, 1, 4, 1>
        <<<dim3(256, 4), 256, 0, stream>>>(a5, bp6, c6);
    {
        int total = 128 * 512 * 16;
        pool6_ht_kernel<<<(total + 255) / 256, 256, 0, stream>>>(
            c6, bn_g[5], bn_b[5], bn_m[5], bn_v[5], h6);
    }
    classifier_kernel<<<128, 256, 0, stream>>>(h6, wlin, out);
}

// Round 7
// 1399.438 us; speedup vs baseline: 1.3329x; 1.2274x over previous
//
#include <hip/hip_runtime.h>
#include <stdint.h>

#define EPS 1e-5f

typedef __attribute__((ext_vector_type(4))) int i32x4;

// ---------------------------------------------------------------------------
// conv1 -> a1: fp32 conv 3->384 + BN + sign, output i8 +-1 into padded NHWC
// a1[n][y+1][x+1][co], borders pre-zeroed by memset.
// ---------------------------------------------------------------------------
__global__ void conv1_a1_kernel(const float* __restrict__ x,
                                const float* __restrict__ w1,
                                const float* __restrict__ g,
                                const float* __restrict__ b,
                                const float* __restrict__ m,
                                const float* __restrict__ v,
                                char* __restrict__ a1)
{
    int bid = blockIdx.x;
    int n = bid >> 5;
    int y = bid & 31;
    int tid = threadIdx.x;
    int xo = tid & 31;
    int cog = tid >> 5;   // 0..11

    float a[27];
#pragma unroll
    for (int ci = 0; ci < 3; ++ci)
#pragma unroll
        for (int dy = 0; dy < 3; ++dy)
#pragma unroll
            for (int dx = 0; dx < 3; ++dx) {
                int yy = y + dy - 1, xx = xo + dx - 1;
                float val = 0.f;
                if (yy >= 0 && yy < 32 && xx >= 0 && xx < 32)
                    val = x[((n * 3 + ci) * 32 + yy) * 32 + xx];
                a[(ci * 3 + dy) * 3 + dx] = val;
            }

    uint32_t w4[8];
#pragma unroll
    for (int i = 0; i < 8; ++i) w4[i] = 0;
    for (int cs = 0; cs < 32; ++cs) {
        int co = cog * 32 + cs;
        const float* wp = w1 + co * 27;
        float acc = 0.f;
#pragma unroll
        for (int i = 0; i < 27; ++i) acc += a[i] * wp[i];
        float t = (acc - m[co]) * (g[co] * rsqrtf(v[co] + EPS)) + b[co];
        uint32_t byte = (t >= 0.f) ? 0x01u : 0xFFu;
        w4[cs >> 2] |= byte << (8 * (cs & 3));
    }
    char* dst = a1 + (((size_t)(n * 34 + y + 1) * 34 + (xo + 1)) * 384 + cog * 32);
    ((uint4*)dst)[0] = make_uint4(w4[0], w4[1], w4[2], w4[3]);
    ((uint4*)dst)[1] = make_uint4(w4[4], w4[5], w4[6], w4[7]);
}

// ---------------------------------------------------------------------------
// B repack into fragment order: Bp[s][col][fg*16+t], s = tap*KC+kc,
// element = sign(w[col][ci=kc*64+fg*16+t][tap]).  Per-step wave loads are
// fully-coalesced 1KB bursts. Buffer padded by one step for branchless
// prefetch.
// ---------------------------------------------------------------------------
__global__ void pack_bp_kernel(const float* __restrict__ w,
                               char* __restrict__ bp, int Co, int Ci)
{
    int KC = Ci >> 6;
    int idx = blockIdx.x * 256 + threadIdx.x;
    int total = Co * 9 * Ci;
    if (idx >= total) return;
    int t  = idx & 15;
    int fg = (idx >> 4) & 3;
    int co = (idx >> 6) % Co;
    int s  = idx / (Co * 64);
    int tap = s / KC, kc = s % KC;
    int ci = kc * 64 + fg * 16 + t;
    bp[idx] = (w[((size_t)co * Ci + ci) * 9 + tap] >= 0.f) ? 1 : -1;
}

// ---------------------------------------------------------------------------
// gemm_db: unified double-buffered implicit-GEMM binary conv (i8 MFMA).
// M-tile 128 (pixels), N-tile 128 (cout), K-step 64 (one tap-chunk).
// A: re-staged per step into lds[2][128*64] (reg-staged, XOR-16B swizzle:
//    sub16 ^= row&3 on BOTH write and read -> conflict-minimal ds ops).
// B: registers, branchless one-step prefetch from padded fragment-order Bp.
// 4 waves (2x2), wave tile 64x64 = 4x4 16x16x64 frags = 16 MFMA/step/wave.
// One barrier per K-step (write buf^1 after MFMAs on buf, then sync).
// ---------------------------------------------------------------------------
template<int Ci, int Co, int H, int W>
__global__ __launch_bounds__(256, 2) void gemm_db_kernel(
    const char* __restrict__ A,
    const char* __restrict__ Bp,
    short* __restrict__ Cc)
{
    constexpr int KC = Ci / 64;
    constexpr int S  = 9 * KC;
    constexpr int WP = W + 2;

    __shared__ __align__(16) char lds[2][128 * 64];

    const int bm = blockIdx.x, bn = blockIdx.y;
    const int tid = threadIdx.x;
    const int lane = tid & 63;
    const int wave = tid >> 6;
    const int wm = wave >> 1, wn = wave & 1;
    const int fr = lane & 15, fg = lane >> 4;

    // staging role: row pl (0..127), half h (0..1) -> 32B each
    const int pl = tid >> 1, h = tid & 1;
    {
        // nothing
    }
    int gm = bm * 128 + pl;
    int n  = gm / (H * W);
    int rr = gm % (H * W);
    int y  = rr / W, x = rr % W;
    const char* abase = A + ((size_t)(n * (H + 2) + y) * WP + x) * Ci + h * 32;
    const int wa0 = pl * 64 + (((2 * h) ^ (pl & 3)) << 4);
    const int wa1 = pl * 64 + (((2 * h + 1) ^ (pl & 3)) << 4);

    int ra[4];
#pragma unroll
    for (int i = 0; i < 4; ++i) {
        int row = wm * 64 + i * 16 + fr;
        ra[i] = row * 64 + ((fg ^ (row & 3)) << 4);
    }

    size_t boff[4];
#pragma unroll
    for (int j = 0; j < 4; ++j) {
        int col = bn * 128 + wn * 64 + j * 16 + fr;
        boff[j] = (size_t)col * 64 + (size_t)fg * 16;
    }
    const size_t bstep = (size_t)Co * 64;

    i32x4 acc[4][4] = {};

    // prologue: A(0) -> lds[0], B(0) -> bf
    {
        uint4 av0 = *reinterpret_cast<const uint4*>(abase);
        uint4 av1 = *reinterpret_cast<const uint4*>(abase + 16);
        *reinterpret_cast<uint4*>(&lds[0][wa0]) = av0;
        *reinterpret_cast<uint4*>(&lds[0][wa1]) = av1;
    }
    i32x4 bf[4];
#pragma unroll
    for (int j = 0; j < 4; ++j)
        bf[j] = *reinterpret_cast<const i32x4*>(Bp + boff[j]);
    __syncthreads();

    for (int s = 0; s < S; ++s) {
        const int cur = s & 1;
        const bool more = (s + 1 < S);
        uint4 avn0, avn1;
        if (more) {
            int s1 = s + 1;
            int tap = s1 / KC, kc = s1 % KC;
            const char* src = abase + ((tap / 3) * WP + (tap % 3)) * Ci + kc * 64;
            avn0 = *reinterpret_cast<const uint4*>(src);
            avn1 = *reinterpret_cast<const uint4*>(src + 16);
        }
        i32x4 bfn[4];
#pragma unroll
        for (int j = 0; j < 4; ++j)
            bfn[j] = *reinterpret_cast<const i32x4*>(
                Bp + (size_t)(s + 1) * bstep + boff[j]);

        i32x4 af[4];
#pragma unroll
        for (int i = 0; i < 4; ++i)
            af[i] = *reinterpret_cast<const i32x4*>(&lds[cur][ra[i]]);
#pragma unroll
        for (int i = 0; i < 4; ++i)
#pragma unroll
            for (int j = 0; j < 4; ++j)
                acc[i][j] = __builtin_amdgcn_mfma_i32_16x16x64_i8(
                    af[i], bf[j], acc[i][j], 0, 0, 0);

        if (more) {
            *reinterpret_cast<uint4*>(&lds[cur ^ 1][wa0]) = avn0;
            *reinterpret_cast<uint4*>(&lds[cur ^ 1][wa1]) = avn1;
        }
#pragma unroll
        for (int j = 0; j < 4; ++j) bf[j] = bfn[j];
        __syncthreads();
    }

    // epilogue: frag row = i*16 + fg*4 + r, col = j*16 + fr (R4/R5-verified)
#pragma unroll
    for (int i = 0; i < 4; ++i) {
#pragma unroll
        for (int r = 0; r < 4; ++r) {
            int p = bm * 128 + wm * 64 + i * 16 + fg * 4 + r;
            int nn = p / (H * W);
            int r2 = p % (H * W);
            size_t crow = ((size_t)(nn * H + r2 / W) * W + r2 % W) * Co;
#pragma unroll
            for (int j = 0; j < 4; ++j) {
                int col = bn * 128 + wn * 64 + j * 16 + fr;
                Cc[crow + col] = (short)acc[i][j][r];
            }
        }
    }
}

// ---------------------------------------------------------------------------
// pool(optional 2x2) + BN + sign -> i8 +-1 padded NHWC for next layer
// ---------------------------------------------------------------------------
__global__ void pool_sign_kernel(const short* __restrict__ c,
                                 const float* __restrict__ g,
                                 const float* __restrict__ b,
                                 const float* __restrict__ m,
                                 const float* __restrict__ v,
                                 char* __restrict__ outp,
                                 int H, int W, int Ho, int Wo, int Co,
                                 int pool, int total)
{
    int idx = blockIdx.x * 256 + threadIdx.x;
    if (idx >= total) return;
    int co = idx % Co;
    int t  = idx / Co;
    int xo = t % Wo; t /= Wo;
    int yo = t % Ho;
    int n  = t / Ho;
    int best;
    if (pool) {
        int m00 = c[((size_t)((n * H + 2 * yo) * W + 2 * xo)) * Co + co];
        int m01 = c[((size_t)((n * H + 2 * yo) * W + 2 * xo + 1)) * Co + co];
        int m10 = c[((size_t)((n * H + 2 * yo + 1) * W + 2 * xo)) * Co + co];
        int m11 = c[((size_t)((n * H + 2 * yo + 1) * W + 2 * xo + 1)) * Co + co];
        best = max(max(m00, m01), max(m10, m11));
    } else {
        best = c[((size_t)((n * H + yo) * W + xo)) * Co + co];
    }
    float tt = ((float)best - m[co]) * (g[co] * rsqrtf(v[co] + EPS)) + b[co];
    outp[((size_t)(n * (Ho + 2) + yo + 1) * (Wo + 2) + xo + 1) * Co + co] =
        tt >= 0.f ? 1 : -1;
}

// ---------------------------------------------------------------------------
// final: pool 2x2 + BN + hardtanh -> fp32 NCHW h6[n][co][yo][xo] (4x4)
// ---------------------------------------------------------------------------
__global__ void pool6_ht_kernel(const short* __restrict__ c,
                                const float* __restrict__ g,
                                const float* __restrict__ b,
                                const float* __restrict__ m,
                                const float* __restrict__ v,
                                float* __restrict__ h6)
{
    int idx = blockIdx.x * 256 + threadIdx.x;
    if (idx >= 128 * 512 * 16) return;
    int xo = idx & 3;
    int yo = (idx >> 2) & 3;
    int t  = idx >> 4;
    int co = t % 512;
    int n  = t / 512;
    int m00 = c[((size_t)((n * 8 + 2 * yo) * 8 + 2 * xo)) * 512 + co];
    int m01 = c[((size_t)((n * 8 + 2 * yo) * 8 + 2 * xo + 1)) * 512 + co];
    int m10 = c[((size_t)((n * 8 + 2 * yo + 1) * 8 + 2 * xo)) * 512 + co];
    int m11 = c[((size_t)((n * 8 + 2 * yo + 1) * 8 + 2 * xo + 1)) * 512 + co];
    int best = max(max(m00, m01), max(m10, m11));
    float tt = ((float)best - m[co]) * (g[co] * rsqrtf(v[co] + EPS)) + b[co];
    tt = fminf(1.f, fmaxf(-1.f, tt));
    h6[((size_t)(n * 512 + co) * 4 + yo) * 4 + xo] = tt;
}

// ---------------------------------------------------------------------------
// classifier: logits = h @ w_lin.T (128 x 8192 x 10) then log_softmax
// ---------------------------------------------------------------------------
__global__ void classifier_kernel(const float* __restrict__ h,
                                  const float* __restrict__ wl,
                                  float* __restrict__ out)
{
    int n = blockIdx.x;
    int tid = threadIdx.x;
    float acc[10];
#pragma unroll
    for (int j = 0; j < 10; ++j) acc[j] = 0.f;
    for (int k = tid; k < 8192; k += 256) {
        float hv = h[n * 8192 + k];
#pragma unroll
        for (int j = 0; j < 10; ++j) acc[j] += hv * wl[j * 8192 + k];
    }
    __shared__ float sred[256];
    __shared__ float logit[10];
    for (int j = 0; j < 10; ++j) {
        sred[tid] = acc[j];
        __syncthreads();
        for (int s = 128; s > 0; s >>= 1) {
            if (tid < s) sred[tid] += sred[tid + s];
            __syncthreads();
        }
        if (tid == 0) logit[j] = sred[0];
        __syncthreads();
    }
    if (tid == 0) {
        float mx = logit[0];
#pragma unroll
        for (int j = 1; j < 10; ++j) mx = fmaxf(mx, logit[j]);
        float s = 0.f;
#pragma unroll
        for (int j = 0; j < 10; ++j) s += expf(logit[j] - mx);
        float lse = logf(s) + mx;
#pragma unroll
        for (int j = 0; j < 10; ++j) out[n * 10 + j] = logit[j] - lse;
    }
}

// ===========================================================================
extern "C" void kernel_launch(void* const* d_in, const int* in_sizes, int n_in,
                              void* d_out, int out_size, void* d_ws, size_t ws_size,
                              hipStream_t stream)
{
    const float* x    = (const float*)d_in[0];
    const float* w1   = (const float*)d_in[1];
    const float* w2   = (const float*)d_in[2];
    const float* w3   = (const float*)d_in[3];
    const float* w4   = (const float*)d_in[4];
    const float* w5   = (const float*)d_in[5];
    const float* w6   = (const float*)d_in[6];
    const float* bn_g[6], *bn_b[6], *bn_m[6], *bn_v[6];
    for (int i = 0; i < 6; ++i) {
        bn_g[i] = (const float*)d_in[7 + i * 4 + 0];
        bn_b[i] = (const float*)d_in[7 + i * 4 + 1];
        bn_m[i] = (const float*)d_in[7 + i * 4 + 2];
        bn_v[i] = (const float*)d_in[7 + i * 4 + 3];
    }
    const float* wlin = (const float*)d_in[31];
    float* out = (float*)d_out;

    // rotating activation/conv-out slots (R4/R5-verified liveness plan)
    const size_t A1 = (size_t)128 * 34 * 34 * 384;     // 56.8 MB
    const size_t A2 = (size_t)128 * 18 * 18 * 384;
    const size_t A3 = (size_t)128 * 18 * 18 * 768;
    const size_t A4 = (size_t)128 * 10 * 10 * 768;
    const size_t A5 = (size_t)128 * 10 * 10 * 1536;
    const size_t C2 = (size_t)131072 * 384 * 2;        // 100.7 MB
    const size_t C4 = (size_t)32768 * 768 * 2;         // 50.3 MB
    const size_t S0 = A1;                              // holds a1,c3,a4,c6
    const size_t S1 = C2;                              // holds c2,a3,c5,h6
    const size_t S2 = C4;                              // holds a2,c4,a5

    char* ws = (char*)d_ws;
    auto alloc = [&](size_t bytes) {
        char* p = ws;
        ws += (bytes + 255) & ~(size_t)255;
        return p;
    };
    char* s0 = (char*)alloc(S0);
    char* s1 = (char*)alloc(S1);
    char* s2 = (char*)alloc(S2);
    // B packs, padded by one K-step (branchless prefetch reads one past end)
    char* bp2 = (char*)alloc((size_t)(9 * 6 + 1) * 384 * 64);
    char* bp3 = (char*)alloc((size_t)(9 * 6 + 1) * 768 * 64);
    char* bp4 = (char*)alloc((size_t)(9 * 12 + 1) * 768 * 64);
    char* bp5 = (char*)alloc((size_t)(9 * 12 + 1) * 1536 * 64);
    char* bp6 = (char*)alloc((size_t)(9 * 24 + 1) * 512 * 64);

    char*  a1 = s0;
    short* c2 = (short*)s1;
    char*  a2 = s2;
    short* c3 = (short*)s0;
    char*  a3 = s1;
    short* c4 = (short*)s2;
    char*  a4 = s0;
    short* c5 = (short*)s1;
    char*  a5 = s2;
    short* c6 = (short*)s0;
    float* h6 = (float*)s1;

    // B repacks
    {
        int t;
        t = 384 * 9 * 384;
        pack_bp_kernel<<<(t + 255) / 256, 256, 0, stream>>>(w2, bp2, 384, 384);
        t = 768 * 9 * 384;
        pack_bp_kernel<<<(t + 255) / 256, 256, 0, stream>>>(w3, bp3, 768, 384);
        t = 768 * 9 * 768;
        pack_bp_kernel<<<(t + 255) / 256, 256, 0, stream>>>(w4, bp4, 768, 768);
        t = 1536 * 9 * 768;
        pack_bp_kernel<<<(t + 255) / 256, 256, 0, stream>>>(w5, bp5, 1536, 768);
        t = 512 * 9 * 1536;
        pack_bp_kernel<<<(t + 255) / 256, 256, 0, stream>>>(w6, bp6, 512, 1536);
    }

    // block 1 -> a1 (padded i8)
    hipMemsetAsync(a1, 0, A1, stream);
    conv1_a1_kernel<<<128 * 32, 384, 0, stream>>>(
        x, w1, bn_g[0], bn_b[0], bn_m[0], bn_v[0], a1);

    // L2: 384->384 @32x32
    gemm_db_kernel<384, 384, 32, 32><<<dim3(1024, 3), 256, 0, stream>>>(a1, bp2, c2);
    hipMemsetAsync(a2, 0, A2, stream);
    {
        int total = 128 * 16 * 16 * 384;
        pool_sign_kernel<<<(total + 255) / 256, 256, 0, stream>>>(
            c2, bn_g[1], bn_b[1], bn_m[1], bn_v[1], a2, 32, 32, 16, 16, 384, 1, total);
    }
    // L3: 384->768 @16x16
    gemm_db_kernel<384, 768, 16, 16><<<dim3(256, 6), 256, 0, stream>>>(a2, bp3, c3);
    hipMemsetAsync(a3, 0, A3, stream);
    {
        int total = 128 * 16 * 16 * 768;
        pool_sign_kernel<<<(total + 255) / 256, 256, 0, stream>>>(
            c3, bn_g[2], bn_b[2], bn_m[2], bn_v[2], a3, 16, 16, 16, 16, 768, 0, total);
    }
    // L4: 768->768 @16x16
    gemm_db_kernel<768, 768, 16, 16><<<dim3(256, 6), 256, 0, stream>>>(a3, bp4, c4);
    hipMemsetAsync(a4, 0, A4, stream);
    {
        int total = 128 * 8 * 8 * 768;
        pool_sign_kernel<<<(total + 255) / 256, 256, 0, stream>>>(
            c4, bn_g[3], bn_b[3], bn_m[3], bn_v[3], a4, 16, 16, 8, 8, 768, 1, total);
    }
    // L5: 768->1536 @8x8
    gemm_db_kernel<768, 1536, 8, 8><<<dim3(64, 12), 256, 0, stream>>>(a4, bp5, c5);
    hipMemsetAsync(a5, 0, A5, stream);
    {
        int total = 128 * 8 * 8 * 1536;
        pool_sign_kernel<<<(total + 255) / 256, 256, 0, stream>>>(
            c5, bn_g[4], bn_b[4], bn_m[4], bn_v[4], a5, 8, 8, 8, 8, 1536, 0, total);
    }
    // L6: 1536->512 @8x8
    gemm_db_kernel<1536, 512, 8, 8><<<dim3(64, 4), 256, 0, stream>>>(a5, bp6, c6);
    {
        int total = 128 * 512 * 16;
        pool6_ht_kernel<<<(total + 255) / 256, 256, 0, stream>>>(
            c6, bn_g[5], bn_b[5], bn_m[5], bn_v[5], h6);
    }
    classifier_kernel<<<128, 256, 0, stream>>>(h6, wlin, out);
}

// Round 8
// 1362.769 us; speedup vs baseline: 1.3687x; 1.0269x over previous
//
#include <hip/hip_runtime.h>
#include <stdint.h>

#define EPS 1e-5f

typedef __attribute__((ext_vector_type(4))) int i32x4;

// ---------------------------------------------------------------------------
// conv1 -> a1: fp32 conv 3->384 + BN + sign, output i8 +-1 into padded NHWC
// a1[n][y+1][x+1][co], borders pre-zeroed by memset.
// ---------------------------------------------------------------------------
__global__ void conv1_a1_kernel(const float* __restrict__ x,
                                const float* __restrict__ w1,
                                const float* __restrict__ g,
                                const float* __restrict__ b,
                                const float* __restrict__ m,
                                const float* __restrict__ v,
                                char* __restrict__ a1)
{
    int bid = blockIdx.x;
    int n = bid >> 5;
    int y = bid & 31;
    int tid = threadIdx.x;
    int xo = tid & 31;
    int cog = tid >> 5;   // 0..11

    float a[27];
#pragma unroll
    for (int ci = 0; ci < 3; ++ci)
#pragma unroll
        for (int dy = 0; dy < 3; ++dy)
#pragma unroll
            for (int dx = 0; dx < 3; ++dx) {
                int yy = y + dy - 1, xx = xo + dx - 1;
                float val = 0.f;
                if (yy >= 0 && yy < 32 && xx >= 0 && xx < 32)
                    val = x[((n * 3 + ci) * 32 + yy) * 32 + xx];
                a[(ci * 3 + dy) * 3 + dx] = val;
            }

    uint32_t w4[8];
#pragma unroll
    for (int i = 0; i < 8; ++i) w4[i] = 0;
    for (int cs = 0; cs < 32; ++cs) {
        int co = cog * 32 + cs;
        const float* wp = w1 + co * 27;
        float acc = 0.f;
#pragma unroll
        for (int i = 0; i < 27; ++i) acc += a[i] * wp[i];
        float t = (acc - m[co]) * (g[co] * rsqrtf(v[co] + EPS)) + b[co];
        uint32_t byte = (t >= 0.f) ? 0x01u : 0xFFu;
        w4[cs >> 2] |= byte << (8 * (cs & 3));
    }
    char* dst = a1 + (((size_t)(n * 34 + y + 1) * 34 + (xo + 1)) * 384 + cog * 32);
    ((uint4*)dst)[0] = make_uint4(w4[0], w4[1], w4[2], w4[3]);
    ((uint4*)dst)[1] = make_uint4(w4[4], w4[5], w4[6], w4[7]);
}

// ---------------------------------------------------------------------------
// B repack into fragment order: Bp[s][col][fg*16+t], s = tap*KC+kc,
// element = sign(w[col][ci=kc*64+fg*16+t][tap]).  Padded by one step for
// branchless prefetch.
// ---------------------------------------------------------------------------
__global__ void pack_bp_kernel(const float* __restrict__ w,
                               char* __restrict__ bp, int Co, int Ci)
{
    int KC = Ci >> 6;
    int idx = blockIdx.x * 256 + threadIdx.x;
    int total = Co * 9 * Ci;
    if (idx >= total) return;
    int t  = idx & 15;
    int fg = (idx >> 4) & 3;
    int co = (idx >> 6) % Co;
    int s  = idx / (Co * 64);
    int tap = s / KC, kc = s % KC;
    int ci = kc * 64 + fg * 16 + t;
    bp[idx] = (w[((size_t)co * Ci + ci) * 9 + tap] >= 0.f) ? 1 : -1;
}

// ---------------------------------------------------------------------------
// gemm_db: unified double-buffered implicit-GEMM binary conv (i8 MFMA).
// M-tile 128 (pixels), N-tile 128 (cout), K-step 64 (one tap-chunk).
// LDS swizzle: 16B slot ^= (row>>1)&3 on BOTH write and read ->
//   (row&1, slot) enumerates all 8 bank-spans uniformly: conflict-free
//   b128 reads AND writes (R6 post-mortem: old (row&3) xor left reads
//   4-way / writes 8-way -> 2.1e7 conflict cycles).
// Grid: 1D with bijective XCD chunking: xcd = id&7 owns a contiguous
//   bm-stripe, bn varies fastest -> A-tile reused GN x back-to-back in one
//   XCD's L2 (T1; R6 had 621 MB HBM re-fetch of A).
// B: registers, branchless one-step prefetch from padded fragment-order Bp.
// 4 waves (2x2), wave tile 64x64 = 4x4 16x16x64 frags; 1 barrier/step.
// ---------------------------------------------------------------------------
template<int Ci, int Co, int H, int W, int GN>
__global__ __launch_bounds__(256, 4) void gemm_db_kernel(
    const char* __restrict__ A,
    const char* __restrict__ Bp,
    short* __restrict__ Cc)
{
    constexpr int KC = Ci / 64;
    constexpr int S  = 9 * KC;
    constexpr int WP = W + 2;
    constexpr int GM = (128 * H * W) / 128;   // M blocks

    __shared__ __align__(16) char lds[2][128 * 64];

    // bijective XCD-chunked decode (GM % 8 == 0 for all layers)
    const int id = blockIdx.x;
    const int xcd = id & 7;
    const int s0 = id >> 3;
    const int bm = xcd * (GM / 8) + s0 / GN;
    const int bn = s0 % GN;

    const int tid = threadIdx.x;
    const int lane = tid & 63;
    const int wave = tid >> 6;
    const int wm = wave >> 1, wn = wave & 1;
    const int fr = lane & 15, fg = lane >> 4;

    // staging role: row pl (0..127), half h (0..1) -> 32B each
    const int pl = tid >> 1, h = tid & 1;
    int gm = bm * 128 + pl;
    int n  = gm / (H * W);
    int rr = gm % (H * W);
    int y  = rr / W, x = rr % W;
    const char* abase = A + ((size_t)(n * (H + 2) + y) * WP + x) * Ci + h * 32;
    const int xw = (pl >> 1) & 3;
    const int wa0 = pl * 64 + (((2 * h) ^ xw) << 4);
    const int wa1 = pl * 64 + (((2 * h + 1) ^ xw) << 4);

    int ra[4];
#pragma unroll
    for (int i = 0; i < 4; ++i) {
        int row = wm * 64 + i * 16 + fr;
        ra[i] = row * 64 + ((fg ^ ((row >> 1) & 3)) << 4);
    }

    size_t boff[4];
#pragma unroll
    for (int j = 0; j < 4; ++j) {
        int col = bn * 128 + wn * 64 + j * 16 + fr;
        boff[j] = (size_t)col * 64 + (size_t)fg * 16;
    }
    const size_t bstep = (size_t)Co * 64;

    i32x4 acc[4][4] = {};

    // prologue: A(0) -> lds[0], B(0) -> bf
    {
        uint4 av0 = *reinterpret_cast<const uint4*>(abase);
        uint4 av1 = *reinterpret_cast<const uint4*>(abase + 16);
        *reinterpret_cast<uint4*>(&lds[0][wa0]) = av0;
        *reinterpret_cast<uint4*>(&lds[0][wa1]) = av1;
    }
    i32x4 bf[4];
#pragma unroll
    for (int j = 0; j < 4; ++j)
        bf[j] = *reinterpret_cast<const i32x4*>(Bp + boff[j]);
    __syncthreads();

    for (int s = 0; s < S; ++s) {
        const int cur = s & 1;
        const bool more = (s + 1 < S);
        uint4 avn0, avn1;
        if (more) {
            int s1 = s + 1;
            int tap = s1 / KC, kc = s1 % KC;
            const char* src = abase + ((tap / 3) * WP + (tap % 3)) * Ci + kc * 64;
            avn0 = *reinterpret_cast<const uint4*>(src);
            avn1 = *reinterpret_cast<const uint4*>(src + 16);
        }
        i32x4 bfn[4];
#pragma unroll
        for (int j = 0; j < 4; ++j)
            bfn[j] = *reinterpret_cast<const i32x4*>(
                Bp + (size_t)(s + 1) * bstep + boff[j]);

        i32x4 af[4];
#pragma unroll
        for (int i = 0; i < 4; ++i)
            af[i] = *reinterpret_cast<const i32x4*>(&lds[cur][ra[i]]);
#pragma unroll
        for (int i = 0; i < 4; ++i)
#pragma unroll
            for (int j = 0; j < 4; ++j)
                acc[i][j] = __builtin_amdgcn_mfma_i32_16x16x64_i8(
                    af[i], bf[j], acc[i][j], 0, 0, 0);

        if (more) {
            *reinterpret_cast<uint4*>(&lds[cur ^ 1][wa0]) = avn0;
            *reinterpret_cast<uint4*>(&lds[cur ^ 1][wa1]) = avn1;
        }
#pragma unroll
        for (int j = 0; j < 4; ++j) bf[j] = bfn[j];
        __syncthreads();
    }

    // epilogue: frag row = i*16 + fg*4 + r, col = j*16 + fr (verified map)
#pragma unroll
    for (int i = 0; i < 4; ++i) {
#pragma unroll
        for (int r = 0; r < 4; ++r) {
            int p = bm * 128 + wm * 64 + i * 16 + fg * 4 + r;
            int nn = p / (H * W);
            int r2 = p % (H * W);
            size_t crow = ((size_t)(nn * H + r2 / W) * W + r2 % W) * Co;
#pragma unroll
            for (int j = 0; j < 4; ++j) {
                int col = bn * 128 + wn * 64 + j * 16 + fr;
                Cc[crow + col] = (short)acc[i][j][r];
            }
        }
    }
}

// ---------------------------------------------------------------------------
// pool(optional 2x2) + BN + sign -> i8 +-1 padded NHWC for next layer
// ---------------------------------------------------------------------------
__global__ void pool_sign_kernel(const short* __restrict__ c,
                                 const float* __restrict__ g,
                                 const float* __restrict__ b,
                                 const float* __restrict__ m,
                                 const float* __restrict__ v,
                                 char* __restrict__ outp,
                                 int H, int W, int Ho, int Wo, int Co,
                                 int pool, int total)
{
    int idx = blockIdx.x * 256 + threadIdx.x;
    if (idx >= total) return;
    int co = idx % Co;
    int t  = idx / Co;
    int xo = t % Wo; t /= Wo;
    int yo = t % Ho;
    int n  = t / Ho;
    int best;
    if (pool) {
        int m00 = c[((size_t)((n * H + 2 * yo) * W + 2 * xo)) * Co + co];
        int m01 = c[((size_t)((n * H + 2 * yo) * W + 2 * xo + 1)) * Co + co];
        int m10 = c[((size_t)((n * H + 2 * yo + 1) * W + 2 * xo)) * Co + co];
        int m11 = c[((size_t)((n * H + 2 * yo + 1) * W + 2 * xo + 1)) * Co + co];
        best = max(max(m00, m01), max(m10, m11));
    } else {
        best = c[((size_t)((n * H + yo) * W + xo)) * Co + co];
    }
    float tt = ((float)best - m[co]) * (g[co] * rsqrtf(v[co] + EPS)) + b[co];
    outp[((size_t)(n * (Ho + 2) + yo + 1) * (Wo + 2) + xo + 1) * Co + co] =
        tt >= 0.f ? 1 : -1;
}

// ---------------------------------------------------------------------------
// final: pool 2x2 + BN + hardtanh -> fp32 NCHW h6[n][co][yo][xo] (4x4)
// ---------------------------------------------------------------------------
__global__ void pool6_ht_kernel(const short* __restrict__ c,
                                const float* __restrict__ g,
                                const float* __restrict__ b,
                                const float* __restrict__ m,
                                const float* __restrict__ v,
                                float* __restrict__ h6)
{
    int idx = blockIdx.x * 256 + threadIdx.x;
    if (idx >= 128 * 512 * 16) return;
    int xo = idx & 3;
    int yo = (idx >> 2) & 3;
    int t  = idx >> 4;
    int co = t % 512;
    int n  = t / 512;
    int m00 = c[((size_t)((n * 8 + 2 * yo) * 8 + 2 * xo)) * 512 + co];
    int m01 = c[((size_t)((n * 8 + 2 * yo) * 8 + 2 * xo + 1)) * 512 + co];
    int m10 = c[((size_t)((n * 8 + 2 * yo + 1) * 8 + 2 * xo)) * 512 + co];
    int m11 = c[((size_t)((n * 8 + 2 * yo + 1) * 8 + 2 * xo + 1)) * 512 + co];
    int best = max(max(m00, m01), max(m10, m11));
    float tt = ((float)best - m[co]) * (g[co] * rsqrtf(v[co] + EPS)) + b[co];
    tt = fminf(1.f, fmaxf(-1.f, tt));
    h6[((size_t)(n * 512 + co) * 4 + yo) * 4 + xo] = tt;
}

// ---------------------------------------------------------------------------
// classifier: logits = h @ w_lin.T (128 x 8192 x 10) then log_softmax
// ---------------------------------------------------------------------------
__global__ void classifier_kernel(const float* __restrict__ h,
                                  const float* __restrict__ wl,
                                  float* __restrict__ out)
{
    int n = blockIdx.x;
    int tid = threadIdx.x;
    float acc[10];
#pragma unroll
    for (int j = 0; j < 10; ++j) acc[j] = 0.f;
    for (int k = tid; k < 8192; k += 256) {
        float hv = h[n * 8192 + k];
#pragma unroll
        for (int j = 0; j < 10; ++j) acc[j] += hv * wl[j * 8192 + k];
    }
    __shared__ float sred[256];
    __shared__ float logit[10];
    for (int j = 0; j < 10; ++j) {
        sred[tid] = acc[j];
        __syncthreads();
        for (int s = 128; s > 0; s >>= 1) {
            if (tid < s) sred[tid] += sred[tid + s];
            __syncthreads();
        }
        if (tid == 0) logit[j] = sred[0];
        __syncthreads();
    }
    if (tid == 0) {
        float mx = logit[0];
#pragma unroll
        for (int j = 1; j < 10; ++j) mx = fmaxf(mx, logit[j]);
        float s = 0.f;
#pragma unroll
        for (int j = 0; j < 10; ++j) s += expf(logit[j] - mx);
        float lse = logf(s) + mx;
#pragma unroll
        for (int j = 0; j < 10; ++j) out[n * 10 + j] = logit[j] - lse;
    }
}

// ===========================================================================
extern "C" void kernel_launch(void* const* d_in, const int* in_sizes, int n_in,
                              void* d_out, int out_size, void* d_ws, size_t ws_size,
                              hipStream_t stream)
{
    const float* x    = (const float*)d_in[0];
    const float* w1   = (const float*)d_in[1];
    const float* w2   = (const float*)d_in[2];
    const float* w3   = (const float*)d_in[3];
    const float* w4   = (const float*)d_in[4];
    const float* w5   = (const float*)d_in[5];
    const float* w6   = (const float*)d_in[6];
    const float* bn_g[6], *bn_b[6], *bn_m[6], *bn_v[6];
    for (int i = 0; i < 6; ++i) {
        bn_g[i] = (const float*)d_in[7 + i * 4 + 0];
        bn_b[i] = (const float*)d_in[7 + i * 4 + 1];
        bn_m[i] = (const float*)d_in[7 + i * 4 + 2];
        bn_v[i] = (const float*)d_in[7 + i * 4 + 3];
    }
    const float* wlin = (const float*)d_in[31];
    float* out = (float*)d_out;

    // rotating activation/conv-out slots (R4-R7-verified liveness plan)
    const size_t A1 = (size_t)128 * 34 * 34 * 384;     // 56.8 MB
    const size_t A2 = (size_t)128 * 18 * 18 * 384;
    const size_t A3 = (size_t)128 * 18 * 18 * 768;
    const size_t A4 = (size_t)128 * 10 * 10 * 768;
    const size_t A5 = (size_t)128 * 10 * 10 * 1536;
    const size_t C2 = (size_t)131072 * 384 * 2;        // 100.7 MB
    const size_t C4 = (size_t)32768 * 768 * 2;         // 50.3 MB
    const size_t S0 = A1;                              // holds a1,c3,a4,c6
    const size_t S1 = C2;                              // holds c2,a3,c5,h6
    const size_t S2 = C4;                              // holds a2,c4,a5

    char* ws = (char*)d_ws;
    auto alloc = [&](size_t bytes) {
        char* p = ws;
        ws += (bytes + 255) & ~(size_t)255;
        return p;
    };
    char* s0 = (char*)alloc(S0);
    char* s1 = (char*)alloc(S1);
    char* s2 = (char*)alloc(S2);
    // B packs, padded by one K-step (branchless prefetch reads one past end)
    char* bp2 = (char*)alloc((size_t)(9 * 6 + 1) * 384 * 64);
    char* bp3 = (char*)alloc((size_t)(9 * 6 + 1) * 768 * 64);
    char* bp4 = (char*)alloc((size_t)(9 * 12 + 1) * 768 * 64);
    char* bp5 = (char*)alloc((size_t)(9 * 12 + 1) * 1536 * 64);
    char* bp6 = (char*)alloc((size_t)(9 * 24 + 1) * 512 * 64);

    char*  a1 = s0;
    short* c2 = (short*)s1;
    char*  a2 = s2;
    short* c3 = (short*)s0;
    char*  a3 = s1;
    short* c4 = (short*)s2;
    char*  a4 = s0;
    short* c5 = (short*)s1;
    char*  a5 = s2;
    short* c6 = (short*)s0;
    float* h6 = (float*)s1;

    // B repacks
    {
        int t;
        t = 384 * 9 * 384;
        pack_bp_kernel<<<(t + 255) / 256, 256, 0, stream>>>(w2, bp2, 384, 384);
        t = 768 * 9 * 384;
        pack_bp_kernel<<<(t + 255) / 256, 256, 0, stream>>>(w3, bp3, 768, 384);
        t = 768 * 9 * 768;
        pack_bp_kernel<<<(t + 255) / 256, 256, 0, stream>>>(w4, bp4, 768, 768);
        t = 1536 * 9 * 768;
        pack_bp_kernel<<<(t + 255) / 256, 256, 0, stream>>>(w5, bp5, 1536, 768);
        t = 512 * 9 * 1536;
        pack_bp_kernel<<<(t + 255) / 256, 256, 0, stream>>>(w6, bp6, 512, 1536);
    }

    // block 1 -> a1 (padded i8)
    hipMemsetAsync(a1, 0, A1, stream);
    conv1_a1_kernel<<<128 * 32, 384, 0, stream>>>(
        x, w1, bn_g[0], bn_b[0], bn_m[0], bn_v[0], a1);

    // L2: 384->384 @32x32   GM=1024, GN=3
    gemm_db_kernel<384, 384, 32, 32, 3><<<1024 * 3, 256, 0, stream>>>(a1, bp2, c2);
    hipMemsetAsync(a2, 0, A2, stream);
    {
        int total = 128 * 16 * 16 * 384;
        pool_sign_kernel<<<(total + 255) / 256, 256, 0, stream>>>(
            c2, bn_g[1], bn_b[1], bn_m[1], bn_v[1], a2, 32, 32, 16, 16, 384, 1, total);
    }
    // L3: 384->768 @16x16   GM=256, GN=6
    gemm_db_kernel<384, 768, 16, 16, 6><<<256 * 6, 256, 0, stream>>>(a2, bp3, c3);
    hipMemsetAsync(a3, 0, A3, stream);
    {
        int total = 128 * 16 * 16 * 768;
        pool_sign_kernel<<<(total + 255) / 256, 256, 0, stream>>>(
            c3, bn_g[2], bn_b[2], bn_m[2], bn_v[2], a3, 16, 16, 16, 16, 768, 0, total);
    }
    // L4: 768->768 @16x16   GM=256, GN=6
    gemm_db_kernel<768, 768, 16, 16, 6><<<256 * 6, 256, 0, stream>>>(a3, bp4, c4);
    hipMemsetAsync(a4, 0, A4, stream);
    {
        int total = 128 * 8 * 8 * 768;
        pool_sign_kernel<<<(total + 255) / 256, 256, 0, stream>>>(
            c4, bn_g[3], bn_b[3], bn_m[3], bn_v[3], a4, 16, 16, 8, 8, 768, 1, total);
    }
    // L5: 768->1536 @8x8    GM=64, GN=12
    gemm_db_kernel<768, 1536, 8, 8, 12><<<64 * 12, 256, 0, stream>>>(a4, bp5, c5);
    hipMemsetAsync(a5, 0, A5, stream);
    {
        int total = 128 * 8 * 8 * 1536;
        pool_sign_kernel<<<(total + 255) / 256, 256, 0, stream>>>(
            c5, bn_g[4], bn_b[4], bn_m[4], bn_v[4], a5, 8, 8, 8, 8, 1536, 0, total);
    }
    // L6: 1536->512 @8x8    GM=64, GN=4
    gemm_db_kernel<1536, 512, 8, 8, 4><<<64 * 4, 256, 0, stream>>>(a5, bp6, c6);
    {
        int total = 128 * 512 * 16;
        pool6_ht_kernel<<<(total + 255) / 256, 256, 0, stream>>>(
            c6, bn_g[5], bn_b[5], bn_m[5], bn_v[5], h6);
    }
    classifier_kernel<<<128, 256, 0, stream>>>(h6, wlin, out);
}